// Round 12
// baseline (397.589 us; speedup 1.0000x reference)
//
#include <hip/hip_runtime.h>
#include <hip/hip_bf16.h>

// x [B=2, C=16, T=31, H=256, W=256] fp32
#define TDIM 31
#define TS   65536                 // t stride (H*W)
#define CS   (TDIM * TS)           // c stride = 2,031,616
#define BS   (16 * CS)             // b stride
#define NTOT (2 * BS)              // 65,011,712
#define GAP_INV (1.0f / (31.0f * 65536.0f))

typedef __attribute__((ext_vector_type(8))) short short8v;     // 8 bf16 (4 VGPR)
typedef __attribute__((ext_vector_type(4))) float f32x4;       // MFMA C/D
typedef __attribute__((ext_vector_type(8))) unsigned short ushort8v;

__device__ __forceinline__ float frcp(float v){ return __builtin_amdgcn_rcpf(v); }
__device__ __forceinline__ float fexp2_(float v){ return __builtin_amdgcn_exp2f(v); }
__device__ __forceinline__ float ftanh(float x){ float e = fexp2_(x*2.8853900817779268f); return 1.0f - 2.0f*frcp(e+1.0f); }
__device__ __forceinline__ float fsigm(float x){ float e = fexp2_(x*-1.4426950408889634f); return frcp(1.0f+e); }
__device__ __forceinline__ unsigned rhu16(float x){ return (__float_as_uint(x) + 0x8000u) >> 16; }
__device__ __forceinline__ float bf2f(unsigned b){ return __uint_as_float(b << 16); }
// pack [hi16(x1) : hi16(x0)] in one v_perm
__device__ __forceinline__ unsigned pkhi(unsigned u0, unsigned u1){ return __builtin_amdgcn_perm(u1, u0, 0x07060302u); }

// ---------------- kA: gates via MFMA (pure streaming, t-parallel) ----------
// Round-7's verified phase-1 (passed absmax 1.95e-3), minus LDS/barrier/scan:
// block = 4 waves, covers 16 positions x all 31 t; wave wv does units
// u = wv+4k (unit = one t of 16 positions). Per unit: B=[Xhi;Xlo] K-split
// MFMAs for conv1 (both branches, bias as C-init), tanh, conv1->conv2
// transpose via 8 in-wave shuffles, conv2 = 2 MFMAs, quantize
// (z snorm16 | f unorm16) manual pack -> 4 global u32 stores (linear layout,
// same as x). No LDS, no barriers -> waves fully independent.
// NOTE: round 10's v_pk_fma_f32 / v_cvt_pknorm_i16_f32 inline asm FAILED
// correctness (absmax 0.22) -- do not reintroduce without disasm evidence.
__global__ __launch_bounds__(256) void kA_gates(
    const float* __restrict__ x,
    const float* __restrict__ wf1, const float* __restrict__ bf1,
    const float* __restrict__ wf2, const float* __restrict__ bf2,
    const float* __restrict__ ww1, const float* __restrict__ bw1,
    const float* __restrict__ ww2, const float* __restrict__ bw2,
    unsigned int* __restrict__ gates)
{
    const int tid  = threadIdx.x;
    const int lane = tid & 63;
    const int wv   = tid >> 6;             // 0..3
    const int col  = lane & 15;            // A-row (=o) / B-col (=position)
    const int kg   = lane >> 4;            // k-group: k = kg*8 + i
    const bool lok = (kg >= 2);            // lane's B-elems are lo-residuals
    const int blk  = blockIdx.x;
    const int b    = blk >> 12;            // 4096 blocks per batch
    const int p0   = (blk & 4095) << 4;

    // ---- weight A-fragments (built once; K=32 logical) ----
    short8v A1f, A2f, A1w, A2w, Af2, Aw2;
    {
        const int c0 = (kg & 1) * 8;       // kg0/2 -> cols 0-7, kg1/3 -> 8-15
#pragma unroll
        for (int i = 0; i < 8; ++i) {
            const float w1 = wf1[col*16 + c0 + i];
            unsigned u1 = __float_as_uint(w1);
            float lo1 = w1 - __uint_as_float(u1 & 0xFFFF0000u);
            A1f[i] = (short)(u1 >> 16);
            A2f[i] = (short)(__float_as_uint(lo1) >> 16);
            const float w2 = ww1[col*16 + c0 + i];
            unsigned u2 = __float_as_uint(w2);
            float lo2 = w2 - __uint_as_float(u2 & 0xFFFF0000u);
            A1w[i] = (short)(u2 >> 16);
            A2w[i] = (short)(__float_as_uint(lo2) >> 16);
            const float v2f = wf2[col*16 + c0 + i];
            const float v2w = ww2[col*16 + c0 + i];
            Af2[i] = (kg < 2)  ? (short)rhu16(v2f) : (short)0;   // [Wf2 | 0]
            Aw2[i] = (kg >= 2) ? (short)rhu16(v2w) : (short)0;   // [0 | Ww2]
        }
    }
    f32x4 b1fv, b1wv, b2fv, b2wv;          // bias vectors: D row o = kg*4 + r
#pragma unroll
    for (int r = 0; r < 4; ++r) {
        b1fv[r] = bf1[kg*4+r]; b1wv[r] = bw1[kg*4+r];
        b2fv[r] = bf2[kg*4+r]; b2wv[r] = bw2[kg*4+r];
    }

    const int lsrc = col + ((kg & 1) << 5);  // col + ((kg&1)*2)*16
    const unsigned gbase = (unsigned)b * BS + (unsigned)p0 + (unsigned)col;

    auto process = [&](int u, const float* xv) {
        // B-frag: k<16 -> Xhi (trunc), k>=16 -> Xlo (residual); v_perm packing
        unsigned H[4], L[4];
#pragma unroll
        for (int j = 0; j < 4; ++j) {
            const unsigned u0 = __float_as_uint(xv[2*j]);
            const unsigned u1 = __float_as_uint(xv[2*j+1]);
            const float l0 = xv[2*j]   - __uint_as_float(u0 & 0xFFFF0000u);
            const float l1 = xv[2*j+1] - __uint_as_float(u1 & 0xFFFF0000u);
            H[j] = pkhi(u0, u1);
            L[j] = pkhi(__float_as_uint(l0), __float_as_uint(l1));
        }
        uint4 bxu;
        bxu.x = lok ? L[0] : H[0]; bxu.y = lok ? L[1] : H[1];
        bxu.z = lok ? L[2] : H[2]; bxu.w = lok ? L[3] : H[3];
        const short8v bx = __builtin_bit_cast(short8v, bxu);

        f32x4 accf = b1fv, accw = b1wv;    // bias as C-init
        accf = __builtin_amdgcn_mfma_f32_16x16x32_bf16(A1f, bx, accf, 0, 0, 0);
        accf = __builtin_amdgcn_mfma_f32_16x16x32_bf16(A2f, bx, accf, 0, 0, 0);
        accw = __builtin_amdgcn_mfma_f32_16x16x32_bf16(A1w, bx, accw, 0, 0, 0);
        accw = __builtin_amdgcn_mfma_f32_16x16x32_bf16(A2w, bx, accw, 0, 0, 0);

        // activations, packed bf16 pairs per (kg): channels kg*4+{0,1},{2,3}
        const float a0 = ftanh(accf[0]), a1 = ftanh(accf[1]);
        const float a2 = ftanh(accf[2]), a3 = ftanh(accf[3]);
        const float w0 = ftanh(accw[0]), w1 = ftanh(accw[1]);
        const float w2 = ftanh(accw[2]), w3 = ftanh(accw[3]);
        const unsigned afP0 = (rhu16(a1) << 16) | rhu16(a0);
        const unsigned afP1 = (rhu16(a3) << 16) | rhu16(a2);
        const unsigned awP0 = (rhu16(w1) << 16) | rhu16(w0);
        const unsigned awP1 = (rhu16(w3) << 16) | rhu16(w2);

        // conv1->conv2 transpose: 8 in-wave shuffles (ds_bpermute), no LDS.
        const unsigned x0l = __shfl(afP0, lsrc, 64);
        const unsigned x1l = __shfl(afP1, lsrc, 64);
        const unsigned x0h = __shfl(afP0, lsrc + 16, 64);
        const unsigned x1h = __shfl(afP1, lsrc + 16, 64);
        const unsigned y0l = __shfl(awP0, lsrc, 64);
        const unsigned y1l = __shfl(awP1, lsrc, 64);
        const unsigned y0h = __shfl(awP0, lsrc + 16, 64);
        const unsigned y1h = __shfl(awP1, lsrc + 16, 64);
        uint4 b2u;
        b2u.x = lok ? y0l : x0l;           // B2 = [af ; aw] along K
        b2u.y = lok ? y1l : x1l;
        b2u.z = lok ? y0h : x0h;
        b2u.w = lok ? y1h : x1h;
        const short8v b2 = __builtin_bit_cast(short8v, b2u);

        f32x4 acz = b2fv, acw = b2wv;
        acz = __builtin_amdgcn_mfma_f32_16x16x32_bf16(Af2, b2, acz, 0, 0, 0);
        acw = __builtin_amdgcn_mfma_f32_16x16x32_bf16(Aw2, b2, acw, 0, 0, 0);

        // quantize (z snorm16 | f unorm16) -> 4 global u32 stores (linear)
#pragma unroll
        for (int r = 0; r < 4; ++r) {
            const float z = ftanh(acz[r]);
            const float f = fsigm(acw[r]);
            const int   zi = (int)__builtin_rintf(z * 32767.0f);
            const unsigned fu = (unsigned)(f * 65535.0f + 0.5f);
            const unsigned wd = ((unsigned)zi << 16) | (fu & 0xFFFFu);
            gates[gbase + (unsigned)(kg*4 + r) * CS + (unsigned)u * TS] = wd;
        }
    };

    // ---- 4-buffer register prefetch, 3 units (~1000 cy) ahead ----
    const unsigned xbase = (unsigned)b * BS + (unsigned)p0 + (unsigned)col
                         + (unsigned)((kg & 1) * 8) * CS;
#define LOADU(dst, u_) { const float* xp = x + (size_t)xbase + (size_t)(u_) * TS; \
    _Pragma("unroll") for (int i = 0; i < 8; ++i) (dst)[i] = xp[i * CS]; }

    float xs0[8], xs1[8], xs2[8], xs3[8];
    LOADU(xs0, wv)                       // wv      < 31
    LOADU(xs1, wv + 4)                   // wv+4  <= 7  < 31
    LOADU(xs2, wv + 8)                   // wv+8  <= 11 < 31
#pragma unroll
    for (int k = 0; k < 8; ++k) {
        const int u  = wv + 4 * k;
        const int uf = u + 12;           // load 3 ahead
        switch (k & 3) {
            case 0: if (uf < TDIM) LOADU(xs3, uf) if (u < TDIM) process(u, xs0); break;
            case 1: if (uf < TDIM) LOADU(xs0, uf) if (u < TDIM) process(u, xs1); break;
            case 2: if (uf < TDIM) LOADU(xs1, uf) if (u < TDIM) process(u, xs2); break;
            default:if (uf < TDIM) LOADU(xs2, uf) if (u < TDIM) process(u, xs3); break;
        }
    }
#undef LOADU
}

// ---------------- kB: scan over t (pure streaming) ----------------
// Thread = one (b, c, pos). 31 independent stride-TS gate loads (pipelined),
// register h-chain, h stored bf16 to ws (or f32 in-place over gates when ws
// is too small). Wave-level GAP partial per (b,c).
template<bool BF16H>
__global__ __launch_bounds__(256) void kB_scan(
    unsigned int* __restrict__ gates,       // also f32 h output when !BF16H
    unsigned short* __restrict__ hb,
    float* __restrict__ partials)
{
    const int pos = blockIdx.x * 256 + threadIdx.x;   // 0..65535
    const int c   = blockIdx.y;                       // 0..15
    const int b   = blockIdx.z;                       // 0..1
    const unsigned base = (unsigned)b * BS + (unsigned)c * CS + (unsigned)pos;

    float h = 0.f, s = 0.f;
#pragma unroll
    for (int t = 0; t < TDIM; ++t) {
        const unsigned wd = gates[base + (unsigned)t * TS];
        const float z = (float)((int)wd >> 16) * (1.0f / 32767.0f);
        const float f = (float)(wd & 0xFFFFu) * (1.0f / 65535.0f);
        h = fmaf(f, h - z, z);              // f*h + (1-f)*z
        s += h;
        if (BF16H) hb[base + (unsigned)t * TS] = (unsigned short)rhu16(h);
        else       ((float*)gates)[base + (unsigned)t * TS] = h;   // in-place
    }
#pragma unroll
    for (int off = 32; off; off >>= 1) s += __shfl_down(s, off, 64);
    const int lane = threadIdx.x & 63, wvv = threadIdx.x >> 6;
    if (lane == 0)
        partials[(unsigned)(b * 16 + c) * 1024 + blockIdx.x * 4 + wvv] = s;
}

// ---------------- k2: reduce partials -> att ----------------
__global__ __launch_bounds__(1024) void k2_attention(
    const float* __restrict__ partials, const float* __restrict__ wsca,
    const float* __restrict__ bsca, float* __restrict__ att)
{
    __shared__ float red[32][32];
    __shared__ float gap[32];
    const int tid = threadIdx.x;
    {
        const int bc = tid >> 5, seg = tid & 31;
        float s = 0.f;
        const float* p = partials + (unsigned)bc * 1024 + seg * 32;
#pragma unroll
        for (int j = 0; j < 32; ++j) s += p[j];
        red[bc][seg] = s;
    }
    __syncthreads();
    if (tid < 32) {
        float s = 0.f;
#pragma unroll
        for (int g = 0; g < 32; ++g) s += red[tid][g];
        gap[tid] = s * GAP_INV;
    }
    __syncthreads();
    if (tid < 32) {
        const int b = tid >> 4, o = tid & 15;
        float acc = bsca[o];
#pragma unroll
        for (int c = 0; c < 16; ++c) acc = fmaf(wsca[o*16 + c], gap[b*16 + c], acc);
        att[b*16 + o] = fsigm(acc);
    }
}

// ---------------- k3: scale ----------------
// bf16-h path: read h (bf16, ws), write fp32 out. grid (248, 32) x 1024: exact.
__global__ __launch_bounds__(1024) void k3_scale_b(
    const unsigned short* __restrict__ hb, const float* __restrict__ att,
    float* __restrict__ out)
{
    const int bc = blockIdx.y;
    const float a = att[bc];
    const unsigned i = blockIdx.x * 1024 + threadIdx.x;     // < 253,952 = CS/8
    const size_t base = (size_t)bc * CS;
    const ushort8v v = ((const ushort8v*)(hb + base))[i];
    float4 o1, o2;
    o1.x = bf2f(v[0])*a; o1.y = bf2f(v[1])*a; o1.z = bf2f(v[2])*a; o1.w = bf2f(v[3])*a;
    o2.x = bf2f(v[4])*a; o2.y = bf2f(v[5])*a; o2.z = bf2f(v[6])*a; o2.w = bf2f(v[7])*a;
    float4* op = (float4*)(out + base);
    op[i*2]     = o1;
    op[i*2 + 1] = o2;
}

// fallback: in-place fp32 scale (h already resides in d_out)
__global__ __launch_bounds__(1024) void k3_scale_a(
    const float* __restrict__ att, float* __restrict__ out)
{
    const int bc = blockIdx.y;
    const float a = att[bc];
    const unsigned i = blockIdx.x * 1024 + threadIdx.x;
    float4* op = (float4*)(out + (size_t)bc * CS);
    float4 v1 = op[i*2], v2 = op[i*2 + 1];
    v1.x *= a; v1.y *= a; v1.z *= a; v1.w *= a;
    v2.x *= a; v2.y *= a; v2.z *= a; v2.w *= a;
    op[i*2] = v1; op[i*2 + 1] = v2;
}

extern "C" void kernel_launch(void* const* d_in, const int* in_sizes, int n_in,
                              void* d_out, int out_size, void* d_ws, size_t ws_size,
                              hipStream_t stream) {
    const float* x    = (const float*)d_in[0];
    const float* wf1  = (const float*)d_in[1];
    const float* bf1  = (const float*)d_in[2];
    const float* wf2  = (const float*)d_in[3];
    const float* bf2  = (const float*)d_in[4];
    const float* ww1  = (const float*)d_in[5];
    const float* bw1  = (const float*)d_in[6];
    const float* ww2  = (const float*)d_in[7];
    const float* bw2  = (const float*)d_in[8];
    const float* wsca = (const float*)d_in[9];
    const float* bsca = (const float*)d_in[10];
    float* out = (float*)d_out;

    const size_t hbBytes   = (size_t)NTOT * 2;               // 130,023,424
    const size_t partBytes = (size_t)32 * 1024 * 4;          // 131,072
    const bool bf16h = ws_size >= hbBytes + partBytes + 256;

    // d_out doubles as the gate buffer (u32 per element = exactly out_size);
    // kB consumes gates (and, in the fallback, overwrites them with f32 h);
    // k3 then fully overwrites d_out with the final scaled output.
    unsigned int* gates = (unsigned int*)d_out;
    unsigned short* hb = (unsigned short*)d_ws;
    float* partials = bf16h ? (float*)((char*)d_ws + hbBytes) : (float*)d_ws;
    float* att = partials + 32 * 1024;

    kA_gates<<<8192, 256, 0, stream>>>(
        x, wf1, bf1, wf2, bf2, ww1, bw1, ww2, bw2, gates);

    if (bf16h) {
        kB_scan<true><<<dim3(256, 16, 2), 256, 0, stream>>>(gates, hb, partials);
        k2_attention<<<1, 1024, 0, stream>>>(partials, wsca, bsca, att);
        k3_scale_b<<<dim3(248, 32), 1024, 0, stream>>>(hb, att, out);
    } else {
        kB_scan<false><<<dim3(256, 16, 2), 256, 0, stream>>>(gates, hb, partials);
        k2_attention<<<1, 1024, 0, stream>>>(partials, wsca, bsca, att);
        k3_scale_a<<<dim3(248, 32), 1024, 0, stream>>>(att, out);
    }
}

// Round 13
// 350.635 us; speedup vs baseline: 1.1339x; 1.1339x over previous
//
#include <hip/hip_runtime.h>
#include <hip/hip_bf16.h>

// x [B=2, C=16, T=31, H=256, W=256] fp32
#define TDIM 31
#define TS   65536                 // t stride (H*W)
#define CS   (TDIM * TS)           // c stride = 2,031,616
#define BS   (16 * CS)             // b stride
#define NTOT (2 * BS)              // 65,011,712
#define GAP_INV (1.0f / (31.0f * 65536.0f))

typedef __attribute__((ext_vector_type(8))) unsigned short ushort8v;
typedef float __attribute__((ext_vector_type(2))) f32x2;

__device__ __forceinline__ float frcp(float v){ return __builtin_amdgcn_rcpf(v); }
__device__ __forceinline__ float fexp2_(float v){ return __builtin_amdgcn_exp2f(v); }
__device__ __forceinline__ float ftanh(float x){ float e = fexp2_(x*2.8853900817779268f); return 1.0f - 2.0f*frcp(e+1.0f); }
__device__ __forceinline__ float fsigm(float x){ float e = fexp2_(x*-1.4426950408889634f); return frcp(1.0f+e); }
__device__ __forceinline__ unsigned rhu16(float x){ return (__float_as_uint(x) + 0x8000u) >> 16; }
__device__ __forceinline__ float bf2f(unsigned b){ return __uint_as_float(b << 16); }

// ---------------- kA: gates (pure streaming, t-parallel) ----------------
// Round-9 structure (best measured: 218us, VALUBusy 86%, 0 conflicts) with the
// matvec inner product issued as 2-wide packed FMA via __builtin_elementwise_fma
// (compiler selects v_pk_fma_f32 on gfx950; exact fp32 fma semantics -- NO
// inline asm, round 10's hand-asm failed correctness).
// Thread = one (b, t, pos). All 16 channels in registers; weights via LDS
// f32x2 broadcast (wave-uniform, conflict-free). Writes packed
// (z snorm16 | f unorm16) u32 into `gates` (= d_out used as scratch; k3
// overwrites it completely afterwards). Stride-CS loads/stores coalesce.
__global__ __launch_bounds__(256) void kA_gates(
    const float* __restrict__ x,
    const float* __restrict__ wf1, const float* __restrict__ bf1,
    const float* __restrict__ wf2, const float* __restrict__ bf2,
    const float* __restrict__ ww1, const float* __restrict__ bw1,
    const float* __restrict__ ww2, const float* __restrict__ bw2,
    unsigned int* __restrict__ gates)
{
    __shared__ __align__(8) float sW[4][256];   // wf1, ww1, wf2, ww2 ([o][c])
    __shared__ float sB[4][16];

    const int tid = threadIdx.x;
    sW[0][tid] = wf1[tid]; sW[1][tid] = ww1[tid];
    sW[2][tid] = wf2[tid]; sW[3][tid] = ww2[tid];
    if (tid < 16) {
        sB[0][tid] = bf1[tid]; sB[1][tid] = bw1[tid];
        sB[2][tid] = bf2[tid]; sB[3][tid] = bw2[tid];
    }
    __syncthreads();

    const int pos = blockIdx.x * 256 + tid;     // 0..65535
    const int t   = blockIdx.y;                 // 0..30
    const int b   = blockIdx.z;                 // 0..1
    const unsigned base = (unsigned)b * BS + (unsigned)t * TS + (unsigned)pos;

    f32x2 xv2[8];
#pragma unroll
    for (int q = 0; q < 8; ++q) {
        xv2[q].x = x[base + (unsigned)(2*q)   * CS];
        xv2[q].y = x[base + (unsigned)(2*q+1) * CS];
    }

    // conv1 (both branches) + tanh; activations kept as f32x2 pairs
    f32x2 af2[8], aw2[8];
#pragma unroll
    for (int o = 0; o < 16; ++o) {
        f32x2 a1 = {sB[0][o], 0.f};
        f32x2 a2 = {sB[1][o], 0.f};
#pragma unroll
        for (int q = 0; q < 8; ++q) {
            const f32x2 w1 = *(const f32x2*)&sW[0][o * 16 + q * 2];
            const f32x2 w2 = *(const f32x2*)&sW[1][o * 16 + q * 2];
            a1 = __builtin_elementwise_fma(w1, xv2[q], a1);
            a2 = __builtin_elementwise_fma(w2, xv2[q], a2);
        }
        const float va = ftanh(a1.x + a1.y);
        const float vw = ftanh(a2.x + a2.y);
        if (o & 1) { af2[o >> 1].y = va; aw2[o >> 1].y = vw; }
        else       { af2[o >> 1].x = va; aw2[o >> 1].x = vw; }
    }
    // conv2 (both branches) -> z=tanh, f=sigm -> manual pack -> store
#pragma unroll
    for (int o = 0; o < 16; ++o) {
        f32x2 a1 = {sB[2][o], 0.f};
        f32x2 a2 = {sB[3][o], 0.f};
#pragma unroll
        for (int q = 0; q < 8; ++q) {
            const f32x2 w1 = *(const f32x2*)&sW[2][o * 16 + q * 2];
            const f32x2 w2 = *(const f32x2*)&sW[3][o * 16 + q * 2];
            a1 = __builtin_elementwise_fma(w1, af2[q], a1);
            a2 = __builtin_elementwise_fma(w2, aw2[q], a2);
        }
        const float z = ftanh(a1.x + a1.y);
        const float f = fsigm(a2.x + a2.y);
        const int zi = (int)__builtin_rintf(z * 32767.0f);
        const unsigned fu = (unsigned)(f * 65535.0f + 0.5f);
        gates[base + (unsigned)o * CS] = ((unsigned)zi << 16) | (fu & 0xFFFFu);
    }
}

// ---------------- kB: scan over t (pure streaming) ----------------
// Thread = one (b, c, pos). 31 independent stride-TS gate loads (pipelined),
// register h-chain, h stored bf16 to ws (or f32 in-place over gates when ws
// is too small). Wave-level GAP partial per (b,c).
template<bool BF16H>
__global__ __launch_bounds__(256) void kB_scan(
    unsigned int* __restrict__ gates,       // also f32 h output when !BF16H
    unsigned short* __restrict__ hb,
    float* __restrict__ partials)
{
    const int pos = blockIdx.x * 256 + threadIdx.x;   // 0..65535
    const int c   = blockIdx.y;                       // 0..15
    const int b   = blockIdx.z;                       // 0..1
    const unsigned base = (unsigned)b * BS + (unsigned)c * CS + (unsigned)pos;

    float h = 0.f, s = 0.f;
#pragma unroll
    for (int t = 0; t < TDIM; ++t) {
        const unsigned wd = gates[base + (unsigned)t * TS];
        const float z = (float)((int)wd >> 16) * (1.0f / 32767.0f);
        const float f = (float)(wd & 0xFFFFu) * (1.0f / 65535.0f);
        h = fmaf(f, h - z, z);              // f*h + (1-f)*z
        s += h;
        if (BF16H) hb[base + (unsigned)t * TS] = (unsigned short)rhu16(h);
        else       ((float*)gates)[base + (unsigned)t * TS] = h;   // in-place
    }
#pragma unroll
    for (int off = 32; off; off >>= 1) s += __shfl_down(s, off, 64);
    const int lane = threadIdx.x & 63, wv = threadIdx.x >> 6;
    if (lane == 0)
        partials[(unsigned)(b * 16 + c) * 1024 + blockIdx.x * 4 + wv] = s;
}

// ---------------- k2: reduce partials -> att ----------------
__global__ __launch_bounds__(1024) void k2_attention(
    const float* __restrict__ partials, const float* __restrict__ wsca,
    const float* __restrict__ bsca, float* __restrict__ att)
{
    __shared__ float red[32][32];
    __shared__ float gap[32];
    const int tid = threadIdx.x;
    {
        const int bc = tid >> 5, seg = tid & 31;
        float s = 0.f;
        const float* p = partials + (unsigned)bc * 1024 + seg * 32;
#pragma unroll
        for (int j = 0; j < 32; ++j) s += p[j];
        red[bc][seg] = s;
    }
    __syncthreads();
    if (tid < 32) {
        float s = 0.f;
#pragma unroll
        for (int g = 0; g < 32; ++g) s += red[tid][g];
        gap[tid] = s * GAP_INV;
    }
    __syncthreads();
    if (tid < 32) {
        const int b = tid >> 4, o = tid & 15;
        float acc = bsca[o];
#pragma unroll
        for (int c = 0; c < 16; ++c) acc = fmaf(wsca[o*16 + c], gap[b*16 + c], acc);
        att[b*16 + o] = fsigm(acc);
    }
}

// ---------------- k3: scale ----------------
// bf16-h path: read h (bf16, ws), write fp32 out. grid (248, 32) x 1024: exact.
__global__ __launch_bounds__(1024) void k3_scale_b(
    const unsigned short* __restrict__ hb, const float* __restrict__ att,
    float* __restrict__ out)
{
    const int bc = blockIdx.y;
    const float a = att[bc];
    const unsigned i = blockIdx.x * 1024 + threadIdx.x;     // < 253,952 = CS/8
    const size_t base = (size_t)bc * CS;
    const ushort8v v = ((const ushort8v*)(hb + base))[i];
    float4 o1, o2;
    o1.x = bf2f(v[0])*a; o1.y = bf2f(v[1])*a; o1.z = bf2f(v[2])*a; o1.w = bf2f(v[3])*a;
    o2.x = bf2f(v[4])*a; o2.y = bf2f(v[5])*a; o2.z = bf2f(v[6])*a; o2.w = bf2f(v[7])*a;
    float4* op = (float4*)(out + base);
    op[i*2]     = o1;
    op[i*2 + 1] = o2;
}

// fallback: in-place fp32 scale (h already resides in d_out)
__global__ __launch_bounds__(1024) void k3_scale_a(
    const float* __restrict__ att, float* __restrict__ out)
{
    const int bc = blockIdx.y;
    const float a = att[bc];
    const unsigned i = blockIdx.x * 1024 + threadIdx.x;
    float4* op = (float4*)(out + (size_t)bc * CS);
    float4 v1 = op[i*2], v2 = op[i*2 + 1];
    v1.x *= a; v1.y *= a; v1.z *= a; v1.w *= a;
    v2.x *= a; v2.y *= a; v2.z *= a; v2.w *= a;
    op[i*2] = v1; op[i*2 + 1] = v2;
}

extern "C" void kernel_launch(void* const* d_in, const int* in_sizes, int n_in,
                              void* d_out, int out_size, void* d_ws, size_t ws_size,
                              hipStream_t stream) {
    const float* x    = (const float*)d_in[0];
    const float* wf1  = (const float*)d_in[1];
    const float* bf1  = (const float*)d_in[2];
    const float* wf2  = (const float*)d_in[3];
    const float* bf2  = (const float*)d_in[4];
    const float* ww1  = (const float*)d_in[5];
    const float* bw1  = (const float*)d_in[6];
    const float* ww2  = (const float*)d_in[7];
    const float* bw2  = (const float*)d_in[8];
    const float* wsca = (const float*)d_in[9];
    const float* bsca = (const float*)d_in[10];
    float* out = (float*)d_out;

    const size_t hbBytes   = (size_t)NTOT * 2;               // 130,023,424
    const size_t partBytes = (size_t)32 * 1024 * 4;          // 131,072
    const bool bf16h = ws_size >= hbBytes + partBytes + 256;

    // d_out doubles as the gate buffer (u32 per element = exactly out_size);
    // kB consumes gates (and, in the fallback, overwrites them with f32 h);
    // k3 then fully overwrites d_out with the final scaled output.
    unsigned int* gates = (unsigned int*)d_out;
    unsigned short* hb = (unsigned short*)d_ws;
    float* partials = bf16h ? (float*)((char*)d_ws + hbBytes) : (float*)d_ws;
    float* att = partials + 32 * 1024;

    kA_gates<<<dim3(256, TDIM, 2), 256, 0, stream>>>(
        x, wf1, bf1, wf2, bf2, ww1, bw1, ww2, bw2, gates);

    if (bf16h) {
        kB_scan<true><<<dim3(256, 16, 2), 256, 0, stream>>>(gates, hb, partials);
        k2_attention<<<1, 1024, 0, stream>>>(partials, wsca, bsca, att);
        k3_scale_b<<<dim3(248, 32), 1024, 0, stream>>>(hb, att, out);
    } else {
        kB_scan<false><<<dim3(256, 16, 2), 256, 0, stream>>>(gates, hb, partials);
        k2_attention<<<1, 1024, 0, stream>>>(partials, wsca, bsca, att);
        k3_scale_a<<<dim3(248, 32), 1024, 0, stream>>>(att, out);
    }
}